// Round 4
// baseline (113.012 us; speedup 1.0000x reference)
//
#include <hip/hip_runtime.h>

#define D 16
#define WQT 4        // q-tiles (of 16 queries) per wave -> 64 queries/wave
                     // R10: WQT=4 has the best instruction mix (VALU-busy-time
                     // 19.3us vs 22.2/30.6 for WQT=2/1). Occupancy fixed via
                     // NCHUNK=256 -> grid 8x256=2048 blocks = exactly 8/CU.
#define TILES_MAX 33 // supports nchunk>=192 (33 tiles); nchunk=256 uses 25
#define FIN_QPB 64   // queries per fin block (x 4 segments = 256 threads)

#define LOG2E 1.4426950408889634f
#define LN2   0.6931471805599453f

typedef __attribute__((ext_vector_type(8))) short bf16x8;
typedef __attribute__((ext_vector_type(4))) float f32x4;

__device__ __forceinline__ unsigned short f2bf(float f) {
    unsigned u = __float_as_uint(f);
    unsigned r = (u + 0x7fffu + ((u >> 16) & 1u)) >> 16;
    return (unsigned short)r;
}

// ---------------- fused convert + weight-sum + density partials via MFMA ----------
// part[chunk][q] = sum_{n in chunk} exp2( L*(x_q.d_n) - 0.5*L*|d_n|^2 + log2 w_n )
// wpart[chunk]   = sum_{n in chunk} w_n  (idempotent: all x-blocks write same value)
__global__ __launch_bounds__(256, 8) void dens_kernel(
        const float* __restrict__ X, const float* __restrict__ data,
        const float* __restrict__ w, float* __restrict__ part,
        float* __restrict__ wpart, int Q, int N) {
    // +1 tile pad so the depth-1 prefetch can read one-past-end harmlessly
    __shared__ unsigned short sh_hi[(TILES_MAX + 1) * 256];  // 17.4 KB
    __shared__ float          sh_cn[(TILES_MAX + 1) * 16];   // 2.2 KB
    __shared__ float          ls[4];

    const int lane = threadIdx.x & 63;
    const int wave = threadIdx.x >> 6;
    const int col  = lane & 15;        // A: m-index; C/D: n-index
    const int quad = lane >> 4;
    const int koff = (quad & 1) * 8;   // k-slice within D=16

    const int qg = blockIdx.x * 4 + wave;   // 64 queries per wave

    // ---- this block's n-tile range (tiles of 16 points), runtime chunk count
    const int nch = gridDim.y;
    const int NT = N >> 4;                       // 6250
    const int base = NT / nch, rem = NT % nch;
    const int chunk = blockIdx.y;
    const int tile0 = chunk * base + min(chunk, rem);
    const int cnt = base + (chunk < rem ? 1 : 0);
    const int npts = cnt * 16;
    const int n0 = tile0 * 16;

    // ---- stage: fp32 -> bf16 pack + per-point constant into LDS; weight sum aside
    float ws = 0.f;
    for (int p = threadIdx.x; p < npts; p += 256) {
        const float4* dp = (const float4*)(data + (size_t)(n0 + p) * D);
        float4 v0 = dp[0], v1 = dp[1], v2 = dp[2], v3 = dp[3];
        float vv[16] = {v0.x, v0.y, v0.z, v0.w, v1.x, v1.y, v1.z, v1.w,
                        v2.x, v2.y, v2.z, v2.w, v3.x, v3.y, v3.z, v3.w};
        float dd = 0.f;
        unsigned hp[8];
        #pragma unroll
        for (int j = 0; j < 8; j++) {
            float a = vv[2 * j], b = vv[2 * j + 1];
            dd = fmaf(a, a, fmaf(b, b, dd));
            hp[j] = (unsigned)f2bf(a) | ((unsigned)f2bf(b) << 16);
        }
        uint4* dst = (uint4*)(sh_hi + p * 16);
        dst[0] = make_uint4(hp[0], hp[1], hp[2], hp[3]);
        dst[1] = make_uint4(hp[4], hp[5], hp[6], hp[7]);
        float wn = w[n0 + p];
        ws += wn;
        sh_cn[p] = fmaf(-0.5f * LOG2E, dd, __builtin_amdgcn_logf(wn));
    }
    #pragma unroll
    for (int off = 32; off > 0; off >>= 1) ws += __shfl_down(ws, off, 64);
    if (lane == 0) ls[wave] = ws;

    // ---- A fragments: bf16(L*x) in quads 0,1; zeros in quads 2,3 (K padding)
    bf16x8 afrag[WQT];
    #pragma unroll
    for (int t = 0; t < WQT; t++) {
        int q = (qg * WQT + t) * 16 + col;
        const float* xp = X + (size_t)q * D + koff;
        bf16x8 a;
        #pragma unroll
        for (int j = 0; j < 8; j++)
            a[j] = (quad < 2) ? (short)f2bf(xp[j] * LOG2E) : (short)0;
        afrag[t] = a;
    }

    f32x4 dens[WQT];
    #pragma unroll
    for (int t = 0; t < WQT; t++) dens[t] = (f32x4){0.f, 0.f, 0.f, 0.f};

    __syncthreads();

    if (threadIdx.x == 0)
        wpart[chunk] = (ls[0] + ls[1]) + (ls[2] + ls[3]);

    // ---- main loop: depth-1 LDS prefetch, 4 independent MFMA->exp2 chains
    const int eoff = (col << 4) + koff;          // shorts
    bf16x8 b1 = *(const bf16x8*)(sh_hi + eoff);
    float  c0 = sh_cn[col];
    for (int it = 0; it < cnt; it++) {
        bf16x8 nb1 = *(const bf16x8*)(sh_hi + (it + 1) * 256 + eoff);
        float  nc0 = sh_cn[(it + 1) * 16 + col];
        f32x4 cvec = {c0, c0, c0, c0};
        #pragma unroll
        for (int t = 0; t < WQT; t++) {
            f32x4 s = __builtin_amdgcn_mfma_f32_16x16x32_bf16(afrag[t], b1, cvec, 0, 0, 0);
            f32x4 e;
            #pragma unroll
            for (int r = 0; r < 4; r++)
                e[r] = __builtin_amdgcn_exp2f(s[r]);
            dens[t] += e;                        // packed f32 adds
        }
        b1 = nb1; c0 = nc0;
    }

    // ---- reduce over the 16 n-lanes, plain store (no atomics)
    #pragma unroll
    for (int t = 0; t < WQT; t++) {
        #pragma unroll
        for (int r = 0; r < 4; r++) {
            float v = dens[t][r];
            v += __shfl_xor(v, 1, 64);
            v += __shfl_xor(v, 2, 64);
            v += __shfl_xor(v, 4, 64);
            v += __shfl_xor(v, 8, 64);
            if (col == 0) {
                int q = (qg * WQT + t) * 16 + quad * 4 + r;
                part[(size_t)chunk * Q + q] = v;
            }
        }
    }
}

// ---------------- finalize: parallel chunk reduce + wave-parallel wsum + log ------
// 32 blocks x 256 threads; each block covers 64 queries, 4 threads per query
// (each summing up to 64 chunks, coalesced), LDS combine, 64 threads finalize.
__global__ __launch_bounds__(256) void fin_kernel(
        const float* __restrict__ X, const float* __restrict__ part,
        const float* __restrict__ wpart, float* __restrict__ out, int Q, int nch) {
    __shared__ float sred[4][FIN_QPB];
    __shared__ float swsum;

    const int tid = threadIdx.x;
    const int qi = tid & (FIN_QPB - 1);
    const int seg = tid >> 6;              // which 64-chunk segment (0..3)
    const int q = blockIdx.x * FIN_QPB + qi;

    // partial sum over this segment's chunks (coalesced across qi lanes)
    float a0 = 0.f, a1 = 0.f, a2 = 0.f, a3 = 0.f;
    const int c0 = seg * 64;
    if (c0 < nch) {
        const int cend = min(c0 + 64, nch);
        for (int c = c0; c < cend; c += 4) {
            a0 += part[(size_t)(c + 0) * Q + q];
            a1 += part[(size_t)(c + 1) * Q + q];
            a2 += part[(size_t)(c + 2) * Q + q];
            a3 += part[(size_t)(c + 3) * Q + q];
        }
    }
    sred[seg][qi] = (a0 + a1) + (a2 + a3);

    // wave 0: wsum via strided loads + shuffle reduce (nch chunks)
    if (tid < 64) {
        float wv = 0.f;
        for (int k = tid; k < nch; k += 64) wv += wpart[k];
        #pragma unroll
        for (int off = 32; off > 0; off >>= 1) wv += __shfl_down(wv, off, 64);
        if (tid == 0) swsum = wv;
    }
    __syncthreads();

    if (tid < FIN_QPB) {
        float dsum = (sred[0][tid] + sred[1][tid]) + (sred[2][tid] + sred[3][tid]);
        int qq = blockIdx.x * FIN_QPB + tid;
        const float4* xp = (const float4*)(X + (size_t)qq * D);
        float4 x0 = xp[0], x1 = xp[1], x2 = xp[2], x3 = xp[3];
        float xx = x0.x*x0.x + x0.y*x0.y + x0.z*x0.z + x0.w*x0.w
                 + x1.x*x1.x + x1.y*x1.y + x1.z*x1.z + x1.w*x1.w
                 + x2.x*x2.x + x2.y*x2.y + x2.z*x2.z + x2.w*x2.w
                 + x3.x*x3.x + x3.y*x3.y + x3.z*x3.z + x3.w*x3.w;
        float aq = -0.5f * LOG2E * xx;
        const float ln_norm = -8.f * 1.8378770664093453f;  // ln((2*pi)^-8)
        out[qq] = LN2 * (aq + __builtin_amdgcn_logf(dsum)
                            - __builtin_amdgcn_logf(swsum)) + ln_norm;
    }
}

extern "C" void kernel_launch(void* const* d_in, const int* in_sizes, int n_in,
                              void* d_out, int out_size, void* d_ws, size_t ws_size,
                              hipStream_t stream) {
    const float* X    = (const float*)d_in[0];
    const float* data = (const float*)d_in[1];
    const float* w    = (const float*)d_in[2];
    float* out = (float*)d_out;
    int Q = in_sizes[0] / D;   // 2048
    int N = in_sizes[1] / D;   // 100000

    // Prefer nchunk=256 (grid 8x256 = 2048 blocks = exactly 8/CU, single round);
    // fall back to 192 if the workspace can't hold part[256][Q].
    int nch = ((size_t)(256 * Q + 256) * sizeof(float) <= ws_size) ? 256 : 192;

    // ws layout (floats): [0..nch) wpart, then part (nch*Q floats).
    // Everything written before read each launch -> no memset needed.
    float* wpart = (float*)d_ws;
    float* part  = wpart + nch;

    dim3 grid(Q / (4 * WQT * 16), nch);   // (8, 256) preferred
    dens_kernel<<<grid, 256, 0, stream>>>(X, data, w, part, wpart, Q, N);

    fin_kernel<<<Q / FIN_QPB, 256, 0, stream>>>(X, part, wpart, out, Q, nch);
}

// Round 5
// 103.840 us; speedup vs baseline: 1.0883x; 1.0883x over previous
//
#include <hip/hip_runtime.h>

#define D 16
#define WQT 2        // q-tiles (of 16 queries) per wave -> 32 queries/wave (R2 best)
#define NCHUNK 192   // n-dimension grid split (R2-measured best total: 102.66 us)
#define TILES_MAX 33 // base=32 (+1 for the first `rem` chunks)
#define FIN_QPB 64   // queries per fin block (x 3 segments = 192 threads)

#define LOG2E 1.4426950408889634f
#define LN2   0.6931471805599453f

typedef __attribute__((ext_vector_type(8))) short bf16x8;
typedef __attribute__((ext_vector_type(4))) float f32x4;

__device__ __forceinline__ unsigned short f2bf(float f) {
    unsigned u = __float_as_uint(f);
    unsigned r = (u + 0x7fffu + ((u >> 16) & 1u)) >> 16;
    return (unsigned short)r;
}

// R11: exp2 via Schraudolph bit-trick on the full-rate VALU instead of the
// 32-cyc/wave trans pipe (R1-R4 fit: dens was trans-serialized at 41.6us floor).
// i = (int)(s*2^23 + 126.957*2^23); underflow (s<-126) clamps via integer max.
// Max ln-space error +-0.0298 << 0.125 tolerance. 3 VALU instrs per element.
#define EXP2_MAGIC 1064992512.0f   // 2^23 * 126.957 (minimax-in-log offset)

// ---------------- fused convert + weight-sum + density partials via MFMA ----------
// part[chunk][q] = sum_{n in chunk} exp2( L*(x_q.d_n) - 0.5*L*|d_n|^2 + log2 w_n )
// wpart[chunk]   = sum_{n in chunk} w_n  (idempotent: all 16 x-blocks write same value)
__global__ __launch_bounds__(256, 8) void dens_kernel(
        const float* __restrict__ X, const float* __restrict__ data,
        const float* __restrict__ w, float* __restrict__ part,
        float* __restrict__ wpart, int Q, int N) {
    // +1 tile pad so the depth-1 prefetch can read one-past-end harmlessly
    __shared__ unsigned short sh_hi[(TILES_MAX + 1) * 256];  // 17.4 KB
    __shared__ float          sh_cn[(TILES_MAX + 1) * 16];   // 2.2 KB
    __shared__ float          ls[4];

    const int lane = threadIdx.x & 63;
    const int wave = threadIdx.x >> 6;
    const int col  = lane & 15;        // A: m-index; C/D: n-index
    const int quad = lane >> 4;
    const int koff = (quad & 1) * 8;   // k-slice within D=16

    const int qg = blockIdx.x * 4 + wave;   // 32 queries per wave

    // ---- this block's n-tile range (tiles of 16 points)
    const int NT = N >> 4;                       // 6250
    const int base = NT / NCHUNK, rem = NT % NCHUNK;
    const int chunk = blockIdx.y;
    const int tile0 = chunk * base + min(chunk, rem);
    const int cnt = base + (chunk < rem ? 1 : 0);
    const int npts = cnt * 16;
    const int n0 = tile0 * 16;

    // ---- stage: fp32 -> bf16 pack + per-point constant into LDS; weight sum aside
    float ws = 0.f;
    for (int p = threadIdx.x; p < npts; p += 256) {
        const float4* dp = (const float4*)(data + (size_t)(n0 + p) * D);
        float4 v0 = dp[0], v1 = dp[1], v2 = dp[2], v3 = dp[3];
        float vv[16] = {v0.x, v0.y, v0.z, v0.w, v1.x, v1.y, v1.z, v1.w,
                        v2.x, v2.y, v2.z, v2.w, v3.x, v3.y, v3.z, v3.w};
        float dd = 0.f;
        unsigned hp[8];
        #pragma unroll
        for (int j = 0; j < 8; j++) {
            float a = vv[2 * j], b = vv[2 * j + 1];
            dd = fmaf(a, a, fmaf(b, b, dd));
            hp[j] = (unsigned)f2bf(a) | ((unsigned)f2bf(b) << 16);
        }
        uint4* dst = (uint4*)(sh_hi + p * 16);
        dst[0] = make_uint4(hp[0], hp[1], hp[2], hp[3]);
        dst[1] = make_uint4(hp[4], hp[5], hp[6], hp[7]);
        float wn = w[n0 + p];
        ws += wn;
        sh_cn[p] = fmaf(-0.5f * LOG2E, dd, __builtin_amdgcn_logf(wn));
    }
    #pragma unroll
    for (int off = 32; off > 0; off >>= 1) ws += __shfl_down(ws, off, 64);
    if (lane == 0) ls[wave] = ws;

    // ---- A fragments: bf16(L*x) in quads 0,1; zeros in quads 2,3 (K padding)
    bf16x8 afrag[WQT];
    #pragma unroll
    for (int t = 0; t < WQT; t++) {
        int q = (qg * WQT + t) * 16 + col;
        const float* xp = X + (size_t)q * D + koff;
        bf16x8 a;
        #pragma unroll
        for (int j = 0; j < 8; j++)
            a[j] = (quad < 2) ? (short)f2bf(xp[j] * LOG2E) : (short)0;
        afrag[t] = a;
    }

    f32x4 dens[WQT];
    #pragma unroll
    for (int t = 0; t < WQT; t++) dens[t] = (f32x4){0.f, 0.f, 0.f, 0.f};

    __syncthreads();

    if (threadIdx.x == 0)
        wpart[chunk] = (ls[0] + ls[1]) + (ls[2] + ls[3]);

    // ---- main loop: depth-1 LDS prefetch, MFMA -> bit-trick exp2 -> accumulate
    const int eoff = (col << 4) + koff;          // shorts
    bf16x8 b1 = *(const bf16x8*)(sh_hi + eoff);
    float  c0 = sh_cn[col];
    #pragma unroll 2
    for (int it = 0; it < cnt; it++) {
        bf16x8 nb1 = *(const bf16x8*)(sh_hi + (it + 1) * 256 + eoff);
        float  nc0 = sh_cn[(it + 1) * 16 + col];
        f32x4 cvec = {c0, c0, c0, c0};
        #pragma unroll
        for (int t = 0; t < WQT; t++) {
            f32x4 s = __builtin_amdgcn_mfma_f32_16x16x32_bf16(afrag[t], b1, cvec, 0, 0, 0);
            #pragma unroll
            for (int r = 0; r < 4; r++) {
                float y = fmaf(s[r], 8388608.0f, EXP2_MAGIC);  // s*2^23 + C
                int i = (int)y;                                 // v_cvt_i32_f32
                i = max(i, 0);                                  // underflow -> 0
                dens[t][r] += __int_as_float(i);                // v_add_f32
            }
        }
        b1 = nb1; c0 = nc0;
    }

    // ---- reduce over the 16 n-lanes, plain store (no atomics)
    #pragma unroll
    for (int t = 0; t < WQT; t++) {
        #pragma unroll
        for (int r = 0; r < 4; r++) {
            float v = dens[t][r];
            v += __shfl_xor(v, 1, 64);
            v += __shfl_xor(v, 2, 64);
            v += __shfl_xor(v, 4, 64);
            v += __shfl_xor(v, 8, 64);
            if (col == 0) {
                int q = (qg * WQT + t) * 16 + quad * 4 + r;
                part[(size_t)chunk * Q + q] = v;
            }
        }
    }
}

// ---------------- finalize: parallel chunk reduce + wave-parallel wsum + log ------
// 32 blocks x 192 threads; each block covers 64 queries, 3 threads per query
// (each summing 64 chunks, coalesced), LDS combine, then 64 threads finalize.
__global__ __launch_bounds__(192) void fin_kernel(
        const float* __restrict__ X, const float* __restrict__ part,
        const float* __restrict__ wpart, float* __restrict__ out, int Q) {
    __shared__ float sred[3][FIN_QPB];
    __shared__ float swsum;

    const int tid = threadIdx.x;
    const int qi = tid & (FIN_QPB - 1);
    const int seg = tid >> 6;              // which 64-chunk segment (0..2)
    const int q = blockIdx.x * FIN_QPB + qi;

    // partial sum over this segment's 64 chunks (coalesced across qi lanes)
    float a0 = 0.f, a1 = 0.f, a2 = 0.f, a3 = 0.f;
    const int c0 = seg * 64;
    #pragma unroll 4
    for (int c = 0; c < 64; c += 4) {
        a0 += part[(size_t)(c0 + c + 0) * Q + q];
        a1 += part[(size_t)(c0 + c + 1) * Q + q];
        a2 += part[(size_t)(c0 + c + 2) * Q + q];
        a3 += part[(size_t)(c0 + c + 3) * Q + q];
    }
    sred[seg][qi] = (a0 + a1) + (a2 + a3);

    // wave 0: wsum via 3 loads/lane + shuffle reduce (192 chunks)
    if (tid < 64) {
        float wv = wpart[tid] + wpart[tid + 64] + wpart[tid + 128];
        #pragma unroll
        for (int off = 32; off > 0; off >>= 1) wv += __shfl_down(wv, off, 64);
        if (tid == 0) swsum = wv;
    }
    __syncthreads();

    if (tid < FIN_QPB) {
        float dsum = sred[0][tid] + sred[1][tid] + sred[2][tid];
        int qq = blockIdx.x * FIN_QPB + tid;
        const float4* xp = (const float4*)(X + (size_t)qq * D);
        float4 x0 = xp[0], x1 = xp[1], x2 = xp[2], x3 = xp[3];
        float xx = x0.x*x0.x + x0.y*x0.y + x0.z*x0.z + x0.w*x0.w
                 + x1.x*x1.x + x1.y*x1.y + x1.z*x1.z + x1.w*x1.w
                 + x2.x*x2.x + x2.y*x2.y + x2.z*x2.z + x2.w*x2.w
                 + x3.x*x3.x + x3.y*x3.y + x3.z*x3.z + x3.w*x3.w;
        float aq = -0.5f * LOG2E * xx;
        const float ln_norm = -8.f * 1.8378770664093453f;  // ln((2*pi)^-8)
        out[qq] = LN2 * (aq + __builtin_amdgcn_logf(dsum)
                            - __builtin_amdgcn_logf(swsum)) + ln_norm;
    }
}

extern "C" void kernel_launch(void* const* d_in, const int* in_sizes, int n_in,
                              void* d_out, int out_size, void* d_ws, size_t ws_size,
                              hipStream_t stream) {
    const float* X    = (const float*)d_in[0];
    const float* data = (const float*)d_in[1];
    const float* w    = (const float*)d_in[2];
    float* out = (float*)d_out;
    int Q = in_sizes[0] / D;   // 2048
    int N = in_sizes[1] / D;   // 100000

    // ws layout (floats): [0..NCHUNK) wpart, then part (NCHUNK*Q floats).
    // Everything written before read each launch -> no memset needed.
    float* wpart = (float*)d_ws;
    float* part  = wpart + NCHUNK;

    dim3 grid(Q / (4 * WQT * 16), NCHUNK);   // (16, 192)
    dens_kernel<<<grid, 256, 0, stream>>>(X, data, w, part, wpart, Q, N);

    fin_kernel<<<Q / FIN_QPB, 192, 0, stream>>>(X, part, wpart, out, Q);
}

// Round 6
// 96.575 us; speedup vs baseline: 1.1702x; 1.0752x over previous
//
#include <hip/hip_runtime.h>

#define D 16
#define NCH 256       // n-chunks: grid (16,256)=4096 blocks = 2 even rounds of 8/CU
                      // (R4 proved ws holds part[256][Q])
#define TILES_MAX 13  // ceil(3125/256) = 13 tiles of 32 points
#define FIN_QPB 64    // queries per fin block (x 4 segments = 256 threads)

#define LOG2E 1.4426950408889634f
#define LN2   0.6931471805599453f

// k-half plane stride in shorts: (TILES_MAX+1) tiles * 32 pts * 8 shorts
#define PLANE ((TILES_MAX + 1) * 32 * 8)

typedef __attribute__((ext_vector_type(8)))  short bf16x8;
typedef __attribute__((ext_vector_type(16))) float f32x16;

__device__ __forceinline__ unsigned short f2bf(float f) {
    unsigned u = __float_as_uint(f);
    unsigned r = (u + 0x7fffu + ((u >> 16) & 1u)) >> 16;
    return (unsigned short)r;
}

// R12: 32x32x16 MFMA (K=16=D exactly, no zero-pad K waste). 1 MFMA = 1024 pair
// elems (4x the 16x16x32 path) -> wave-iterations 400K->200K. R1-R5 fit:
// dens = VALU-busy (per-iteration overhead dominated) + stall ~ iterations.
// part[chunk][q] = sum_{n in chunk} exp2( L*(x_q.d_n) - 0.5*L*|d_n|^2 + log2 w_n )
__global__ __launch_bounds__(256, 8) void dens_kernel(
        const float* __restrict__ X, const float* __restrict__ data,
        const float* __restrict__ w, float* __restrict__ part,
        float* __restrict__ wpart, int Q, int N) {
    // two k-half planes so the B-fragment is one ds_read_b128 per tile
    __shared__ unsigned short sh_hi[2 * PLANE];            // 14.3 KB
    __shared__ float          sh_cn[(TILES_MAX + 1) * 32]; // 1.8 KB
    __shared__ float          ls[4];

    const int lane  = threadIdx.x & 63;
    const int wave  = threadIdx.x >> 6;
    const int col32 = lane & 31;       // B col / D col: n-index within tile
    const int khalf = lane >> 5;       // k-half (0: k0-7, 1: k8-15)

    const int qg = blockIdx.x * 4 + wave;   // q-tile of 32 queries per wave

    // ---- this block's n-tile range (tiles of 32 points)
    const int NT = N >> 5;                       // 3125
    const int base = NT / NCH, rem = NT % NCH;
    const int chunk = blockIdx.y;
    const int tile0 = chunk * base + min(chunk, rem);
    const int cnt = base + (chunk < rem ? 1 : 0);
    const int npts = cnt * 32;
    const int n0 = tile0 * 32;

    // ---- stage: fp32 -> bf16 pack into two k-half planes + per-point constant
    float ws = 0.f;
    for (int p = threadIdx.x; p < npts; p += 256) {
        const float4* dp = (const float4*)(data + (size_t)(n0 + p) * D);
        float4 v0 = dp[0], v1 = dp[1], v2 = dp[2], v3 = dp[3];
        float vv[16] = {v0.x, v0.y, v0.z, v0.w, v1.x, v1.y, v1.z, v1.w,
                        v2.x, v2.y, v2.z, v2.w, v3.x, v3.y, v3.z, v3.w};
        float dd = 0.f;
        unsigned hp[8];
        #pragma unroll
        for (int j = 0; j < 8; j++) {
            float a = vv[2 * j], b = vv[2 * j + 1];
            dd = fmaf(a, a, fmaf(b, b, dd));
            hp[j] = (unsigned)f2bf(a) | ((unsigned)f2bf(b) << 16);
        }
        *(uint4*)(sh_hi + p * 8)         = make_uint4(hp[0], hp[1], hp[2], hp[3]);
        *(uint4*)(sh_hi + PLANE + p * 8) = make_uint4(hp[4], hp[5], hp[6], hp[7]);
        float wn = w[n0 + p];
        ws += wn;
        sh_cn[p] = fmaf(-0.5f * LOG2E, dd, __builtin_amdgcn_logf(wn));
    }
    #pragma unroll
    for (int off = 32; off > 0; off >>= 1) ws += __shfl_down(ws, off, 64);
    if (lane == 0) ls[wave] = ws;

    // ---- A fragment: bf16(L*x), row = col32, k = khalf*8 + j  (full K=16 used)
    bf16x8 afrag;
    {
        int q = qg * 32 + col32;
        const float* xp = X + (size_t)q * D + khalf * 8;
        #pragma unroll
        for (int j = 0; j < 8; j++)
            afrag[j] = (short)f2bf(xp[j] * LOG2E);
    }

    f32x16 dens;
    #pragma unroll
    for (int r = 0; r < 16; r++) dens[r] = 0.f;

    __syncthreads();

    if (threadIdx.x == 0)
        wpart[chunk] = (ls[0] + ls[1]) + (ls[2] + ls[3]);

    // ---- main loop: depth-1 LDS prefetch, one 32x32 MFMA -> 16 exp2 -> accumulate
    const int eoff = khalf * PLANE + col32 * 8;  // shorts
    bf16x8 b1 = *(const bf16x8*)(sh_hi + eoff);
    float  c0 = sh_cn[col32];
    #pragma unroll 2
    for (int it = 0; it < cnt; it++) {
        bf16x8 nb1 = *(const bf16x8*)(sh_hi + (it + 1) * 256 + eoff);
        float  nc0 = sh_cn[(it + 1) * 32 + col32];
        f32x16 s;
        #pragma unroll
        for (int r = 0; r < 16; r++) s[r] = c0;     // C = broadcast(c_n), in-place
        s = __builtin_amdgcn_mfma_f32_32x32x16_bf16(afrag, b1, s, 0, 0, 0);
        #pragma unroll
        for (int r = 0; r < 16; r++)
            dens[r] += __builtin_amdgcn_exp2f(s[r]); // trans pipe, overlaps VALU
        b1 = nb1; c0 = nc0;
    }

    // ---- reduce over the 32 n-lanes (cols), plain store (no atomics)
    #pragma unroll
    for (int r = 0; r < 16; r++) {
        float v = dens[r];
        v += __shfl_xor(v, 1, 64);
        v += __shfl_xor(v, 2, 64);
        v += __shfl_xor(v, 4, 64);
        v += __shfl_xor(v, 8, 64);
        v += __shfl_xor(v, 16, 64);
        if (col32 == 0) {
            int q = qg * 32 + (r & 3) + 8 * (r >> 2) + 4 * khalf;
            part[(size_t)chunk * Q + q] = v;
        }
    }
}

// ---------------- finalize: parallel chunk reduce + wave-parallel wsum + log ------
// 32 blocks x 256 threads; each block covers 64 queries, 4 threads per query
// (each summing 64 chunks, coalesced), LDS combine, 64 threads finalize.
__global__ __launch_bounds__(256) void fin_kernel(
        const float* __restrict__ X, const float* __restrict__ part,
        const float* __restrict__ wpart, float* __restrict__ out, int Q) {
    __shared__ float sred[4][FIN_QPB];
    __shared__ float swsum;

    const int tid = threadIdx.x;
    const int qi = tid & (FIN_QPB - 1);
    const int seg = tid >> 6;              // which 64-chunk segment (0..3)
    const int q = blockIdx.x * FIN_QPB + qi;

    // partial sum over this segment's 64 chunks (coalesced across qi lanes)
    float a0 = 0.f, a1 = 0.f, a2 = 0.f, a3 = 0.f;
    const int c0 = seg * 64;
    #pragma unroll 4
    for (int c = 0; c < 64; c += 4) {
        a0 += part[(size_t)(c0 + c + 0) * Q + q];
        a1 += part[(size_t)(c0 + c + 1) * Q + q];
        a2 += part[(size_t)(c0 + c + 2) * Q + q];
        a3 += part[(size_t)(c0 + c + 3) * Q + q];
    }
    sred[seg][qi] = (a0 + a1) + (a2 + a3);

    // wave 0: wsum via 4 loads/lane + shuffle reduce (256 chunks)
    if (tid < 64) {
        float wv = (wpart[tid] + wpart[tid + 64])
                 + (wpart[tid + 128] + wpart[tid + 192]);
        #pragma unroll
        for (int off = 32; off > 0; off >>= 1) wv += __shfl_down(wv, off, 64);
        if (tid == 0) swsum = wv;
    }
    __syncthreads();

    if (tid < FIN_QPB) {
        float dsum = (sred[0][tid] + sred[1][tid]) + (sred[2][tid] + sred[3][tid]);
        int qq = blockIdx.x * FIN_QPB + tid;
        const float4* xp = (const float4*)(X + (size_t)qq * D);
        float4 x0 = xp[0], x1 = xp[1], x2 = xp[2], x3 = xp[3];
        float xx = x0.x*x0.x + x0.y*x0.y + x0.z*x0.z + x0.w*x0.w
                 + x1.x*x1.x + x1.y*x1.y + x1.z*x1.z + x1.w*x1.w
                 + x2.x*x2.x + x2.y*x2.y + x2.z*x2.z + x2.w*x2.w
                 + x3.x*x3.x + x3.y*x3.y + x3.z*x3.z + x3.w*x3.w;
        float aq = -0.5f * LOG2E * xx;
        const float ln_norm = -8.f * 1.8378770664093453f;  // ln((2*pi)^-8)
        out[qq] = LN2 * (aq + __builtin_amdgcn_logf(dsum)
                            - __builtin_amdgcn_logf(swsum)) + ln_norm;
    }
}

extern "C" void kernel_launch(void* const* d_in, const int* in_sizes, int n_in,
                              void* d_out, int out_size, void* d_ws, size_t ws_size,
                              hipStream_t stream) {
    const float* X    = (const float*)d_in[0];
    const float* data = (const float*)d_in[1];
    const float* w    = (const float*)d_in[2];
    float* out = (float*)d_out;
    int Q = in_sizes[0] / D;   // 2048
    int N = in_sizes[1] / D;   // 100000

    // ws layout (floats): [0..NCH) wpart, then part (NCH*Q floats).
    // Everything written before read each launch -> no memset needed.
    float* wpart = (float*)d_ws;
    float* part  = wpart + NCH;

    dim3 grid(Q / (4 * 32), NCH);   // (16, 256)
    dens_kernel<<<grid, 256, 0, stream>>>(X, data, w, part, wpart, Q, N);

    fin_kernel<<<Q / FIN_QPB, 256, 0, stream>>>(X, part, wpart, out, Q);
}

// Round 7
// 92.985 us; speedup vs baseline: 1.2154x; 1.0386x over previous
//
#include <hip/hip_runtime.h>

#define D 16
#define NCH 256       // n-chunks: grid (16,256)=4096 blocks = 2 even rounds of 8/CU
#define TILES_MAX 13  // ceil(3125/256) = 13 tiles of 32 points
#define FIN_QPB 64    // queries per fin block (x 4 segments = 256 threads)

#define LOG2E 1.4426950408889634f
#define LN2   0.6931471805599453f

// k-half plane stride in shorts: (TILES_MAX+1) tiles * 32 pts * 8 shorts
#define PLANE ((TILES_MAX + 1) * 32 * 8)

typedef __attribute__((ext_vector_type(8)))  short bf16x8;
typedef __attribute__((ext_vector_type(16))) float f32x16;

__device__ __forceinline__ unsigned short f2bf(float f) {
    unsigned u = __float_as_uint(f);
    unsigned r = (u + 0x7fffu + ((u >> 16) & 1u)) >> 16;
    return (unsigned short)r;
}

// R13: multiplicative weight fold. exp2(dot + c_n) = p_n * exp2(dot) with
// p_n = w_n * 2^(-0.5*L*|d_n|^2) precomputed in staging. MFMA C-operand is a
// loop-invariant ZERO vector (read-only), killing the per-iteration 16-reg
// C-init + its AGPR write/read traffic (R6 fit: 328 cyc/iter busy vs ~150
// source instrs = accvgpr round-trips). Accumulate = v_fmac per element.
// part[chunk][q] = sum_{n in chunk} p_n * exp2( L*(x_q.d_n) )
__global__ __launch_bounds__(256, 8) void dens_kernel(
        const float* __restrict__ X, const float* __restrict__ data,
        const float* __restrict__ w, float* __restrict__ part,
        float* __restrict__ wpart, int Q, int N) {
    // two k-half planes so the B-fragment is one ds_read_b128 per tile
    __shared__ unsigned short sh_hi[2 * PLANE];            // 14.3 KB
    __shared__ float          sh_p[(TILES_MAX + 1) * 32];  // 1.8 KB
    __shared__ float          ls[4];

    const int lane  = threadIdx.x & 63;
    const int wave  = threadIdx.x >> 6;
    const int col32 = lane & 31;       // B col / D col: n-index within tile
    const int khalf = lane >> 5;       // k-half (0: k0-7, 1: k8-15)

    const int qg = blockIdx.x * 4 + wave;   // q-tile of 32 queries per wave

    // ---- this block's n-tile range (tiles of 32 points)
    const int NT = N >> 5;                       // 3125
    const int base = NT / NCH, rem = NT % NCH;
    const int chunk = blockIdx.y;
    const int tile0 = chunk * base + min(chunk, rem);
    const int cnt = base + (chunk < rem ? 1 : 0);
    const int npts = cnt * 32;
    const int n0 = tile0 * 32;

    // ---- stage: fp32 -> bf16 pack into two k-half planes + per-point weight
    float ws = 0.f;
    for (int p = threadIdx.x; p < npts; p += 256) {
        const float4* dp = (const float4*)(data + (size_t)(n0 + p) * D);
        float4 v0 = dp[0], v1 = dp[1], v2 = dp[2], v3 = dp[3];
        float vv[16] = {v0.x, v0.y, v0.z, v0.w, v1.x, v1.y, v1.z, v1.w,
                        v2.x, v2.y, v2.z, v2.w, v3.x, v3.y, v3.z, v3.w};
        float dd = 0.f;
        unsigned hp[8];
        #pragma unroll
        for (int j = 0; j < 8; j++) {
            float a = vv[2 * j], b = vv[2 * j + 1];
            dd = fmaf(a, a, fmaf(b, b, dd));
            hp[j] = (unsigned)f2bf(a) | ((unsigned)f2bf(b) << 16);
        }
        *(uint4*)(sh_hi + p * 8)         = make_uint4(hp[0], hp[1], hp[2], hp[3]);
        *(uint4*)(sh_hi + PLANE + p * 8) = make_uint4(hp[4], hp[5], hp[6], hp[7]);
        float wn = w[n0 + p];
        ws += wn;
        sh_p[p] = wn * __builtin_amdgcn_exp2f(-0.5f * LOG2E * dd);
    }
    #pragma unroll
    for (int off = 32; off > 0; off >>= 1) ws += __shfl_down(ws, off, 64);
    if (lane == 0) ls[wave] = ws;

    // ---- A fragment: bf16(L*x), row = col32, k = khalf*8 + j  (full K=16 used)
    bf16x8 afrag;
    {
        int q = qg * 32 + col32;
        const float* xp = X + (size_t)q * D + khalf * 8;
        #pragma unroll
        for (int j = 0; j < 8; j++)
            afrag[j] = (short)f2bf(xp[j] * LOG2E);
    }

    f32x16 dens, zc;
    #pragma unroll
    for (int r = 0; r < 16; r++) { dens[r] = 0.f; zc[r] = 0.f; }

    __syncthreads();

    if (threadIdx.x == 0)
        wpart[chunk] = (ls[0] + ls[1]) + (ls[2] + ls[3]);

    // ---- main loop: depth-1 LDS prefetch; MFMA(C=zero) -> exp2 -> fmac(p0)
    const int eoff = khalf * PLANE + col32 * 8;  // shorts
    bf16x8 b1 = *(const bf16x8*)(sh_hi + eoff);
    float  p0 = sh_p[col32];
    #pragma unroll 2
    for (int it = 0; it < cnt; it++) {
        bf16x8 nb1 = *(const bf16x8*)(sh_hi + (it + 1) * 256 + eoff);
        float  np0 = sh_p[(it + 1) * 32 + col32];
        f32x16 s = __builtin_amdgcn_mfma_f32_32x32x16_bf16(afrag, b1, zc, 0, 0, 0);
        #pragma unroll
        for (int r = 0; r < 16; r++)
            dens[r] = fmaf(p0, __builtin_amdgcn_exp2f(s[r]), dens[r]);
        b1 = nb1; p0 = np0;
    }

    // ---- reduce over the 32 n-lanes (cols), plain store (no atomics)
    #pragma unroll
    for (int r = 0; r < 16; r++) {
        float v = dens[r];
        v += __shfl_xor(v, 1, 64);
        v += __shfl_xor(v, 2, 64);
        v += __shfl_xor(v, 4, 64);
        v += __shfl_xor(v, 8, 64);
        v += __shfl_xor(v, 16, 64);
        if (col32 == 0) {
            int q = qg * 32 + (r & 3) + 8 * (r >> 2) + 4 * khalf;
            part[(size_t)chunk * Q + q] = v;
        }
    }
}

// ---------------- finalize: parallel chunk reduce + wave-parallel wsum + log ------
// 32 blocks x 256 threads; each block covers 64 queries, 4 threads per query
// (each summing 64 chunks, coalesced), LDS combine, 64 threads finalize.
__global__ __launch_bounds__(256) void fin_kernel(
        const float* __restrict__ X, const float* __restrict__ part,
        const float* __restrict__ wpart, float* __restrict__ out, int Q) {
    __shared__ float sred[4][FIN_QPB];
    __shared__ float swsum;

    const int tid = threadIdx.x;
    const int qi = tid & (FIN_QPB - 1);
    const int seg = tid >> 6;              // which 64-chunk segment (0..3)
    const int q = blockIdx.x * FIN_QPB + qi;

    // partial sum over this segment's 64 chunks (coalesced across qi lanes)
    float a0 = 0.f, a1 = 0.f, a2 = 0.f, a3 = 0.f;
    const int c0 = seg * 64;
    #pragma unroll 4
    for (int c = 0; c < 64; c += 4) {
        a0 += part[(size_t)(c0 + c + 0) * Q + q];
        a1 += part[(size_t)(c0 + c + 1) * Q + q];
        a2 += part[(size_t)(c0 + c + 2) * Q + q];
        a3 += part[(size_t)(c0 + c + 3) * Q + q];
    }
    sred[seg][qi] = (a0 + a1) + (a2 + a3);

    // wave 0: wsum via 4 loads/lane + shuffle reduce (256 chunks)
    if (tid < 64) {
        float wv = (wpart[tid] + wpart[tid + 64])
                 + (wpart[tid + 128] + wpart[tid + 192]);
        #pragma unroll
        for (int off = 32; off > 0; off >>= 1) wv += __shfl_down(wv, off, 64);
        if (tid == 0) swsum = wv;
    }
    __syncthreads();

    if (tid < FIN_QPB) {
        float dsum = (sred[0][tid] + sred[1][tid]) + (sred[2][tid] + sred[3][tid]);
        int qq = blockIdx.x * FIN_QPB + tid;
        const float4* xp = (const float4*)(X + (size_t)qq * D);
        float4 x0 = xp[0], x1 = xp[1], x2 = xp[2], x3 = xp[3];
        float xx = x0.x*x0.x + x0.y*x0.y + x0.z*x0.z + x0.w*x0.w
                 + x1.x*x1.x + x1.y*x1.y + x1.z*x1.z + x1.w*x1.w
                 + x2.x*x2.x + x2.y*x2.y + x2.z*x2.z + x2.w*x2.w
                 + x3.x*x3.x + x3.y*x3.y + x3.z*x3.z + x3.w*x3.w;
        float aq = -0.5f * LOG2E * xx;
        const float ln_norm = -8.f * 1.8378770664093453f;  // ln((2*pi)^-8)
        out[qq] = LN2 * (aq + __builtin_amdgcn_logf(dsum)
                            - __builtin_amdgcn_logf(swsum)) + ln_norm;
    }
}

extern "C" void kernel_launch(void* const* d_in, const int* in_sizes, int n_in,
                              void* d_out, int out_size, void* d_ws, size_t ws_size,
                              hipStream_t stream) {
    const float* X    = (const float*)d_in[0];
    const float* data = (const float*)d_in[1];
    const float* w    = (const float*)d_in[2];
    float* out = (float*)d_out;
    int Q = in_sizes[0] / D;   // 2048
    int N = in_sizes[1] / D;   // 100000

    // ws layout (floats): [0..NCH) wpart, then part (NCH*Q floats).
    // Everything written before read each launch -> no memset needed.
    float* wpart = (float*)d_ws;
    float* part  = wpart + NCH;

    dim3 grid(Q / (4 * 32), NCH);   // (16, 256)
    dens_kernel<<<grid, 256, 0, stream>>>(X, data, w, part, wpart, Q, N);

    fin_kernel<<<Q / FIN_QPB, 256, 0, stream>>>(X, part, wpart, out, Q);
}

// Round 8
// 91.983 us; speedup vs baseline: 1.2286x; 1.0109x over previous
//
#include <hip/hip_runtime.h>

#define D 16
#define NCH 128       // n-chunks: grid (16,128)=2048 blocks = 2 even rounds of
                      // 4 blocks/CU (the R14 launch_bounds(256,4) regime)
#define TILES_MAX 25  // ceil(3125/128) = 25 tiles of 32 points
#define FIN_QPB 64    // queries per fin block (x 4 segments of 32 chunks)

#define LOG2E 1.4426950408889634f
#define LN2   0.6931471805599453f

// k-half plane stride in shorts: (TILES_MAX+1) tiles * 32 pts * 8 shorts
#define PLANE ((TILES_MAX + 1) * 32 * 8)

typedef __attribute__((ext_vector_type(8)))  short bf16x8;
typedef __attribute__((ext_vector_type(16))) float f32x16;

__device__ __forceinline__ unsigned short f2bf(float f) {
    unsigned u = __float_as_uint(f);
    unsigned r = (u + 0x7fffu + ((u >> 16) & 1u)) >> 16;
    return (unsigned short)r;
}

// R14: kill the AGPR shuffle tax. R7's VGPR_Count=24 with ~70 live values
// proves launch_bounds(256,8) (<=64 VGPR budget) forced dens/s/zc into AGPRs:
// ~130 cyc/iter of accvgpr_read/write round-trips (the unexplained gap in the
// 328 cyc/iter busy fit). launch_bounds(256,4) -> 128 VGPRs -> all-VGPR loop;
// occupancy 8->4 blocks/CU is covered by 16-wide exp/fmac ILP per iteration.
// part[chunk][q] = sum_{n in chunk} p_n * exp2( L*(x_q.d_n) ),
// p_n = w_n * 2^(-0.5*L*|d_n|^2) precomputed in staging (R13 fold).
__global__ __launch_bounds__(256, 4) void dens_kernel(
        const float* __restrict__ X, const float* __restrict__ data,
        const float* __restrict__ w, float* __restrict__ part,
        float* __restrict__ wpart, int Q, int N) {
    // two k-half planes so the B-fragment is one ds_read_b128 per tile
    __shared__ unsigned short sh_hi[2 * PLANE];            // 26.6 KB
    __shared__ float          sh_p[(TILES_MAX + 1) * 32];  // 3.3 KB
    __shared__ float          ls[4];

    const int lane  = threadIdx.x & 63;
    const int wave  = threadIdx.x >> 6;
    const int col32 = lane & 31;       // B col / D col: n-index within tile
    const int khalf = lane >> 5;       // k-half (0: k0-7, 1: k8-15)

    const int qg = blockIdx.x * 4 + wave;   // q-tile of 32 queries per wave

    // ---- this block's n-tile range (tiles of 32 points)
    const int NT = N >> 5;                       // 3125
    const int base = NT / NCH, rem = NT % NCH;
    const int chunk = blockIdx.y;
    const int tile0 = chunk * base + min(chunk, rem);
    const int cnt = base + (chunk < rem ? 1 : 0);
    const int npts = cnt * 32;
    const int n0 = tile0 * 32;

    // ---- stage: fp32 -> bf16 pack into two k-half planes + per-point weight
    float ws = 0.f;
    for (int p = threadIdx.x; p < npts; p += 256) {
        const float4* dp = (const float4*)(data + (size_t)(n0 + p) * D);
        float4 v0 = dp[0], v1 = dp[1], v2 = dp[2], v3 = dp[3];
        float vv[16] = {v0.x, v0.y, v0.z, v0.w, v1.x, v1.y, v1.z, v1.w,
                        v2.x, v2.y, v2.z, v2.w, v3.x, v3.y, v3.z, v3.w};
        float dd = 0.f;
        unsigned hp[8];
        #pragma unroll
        for (int j = 0; j < 8; j++) {
            float a = vv[2 * j], b = vv[2 * j + 1];
            dd = fmaf(a, a, fmaf(b, b, dd));
            hp[j] = (unsigned)f2bf(a) | ((unsigned)f2bf(b) << 16);
        }
        *(uint4*)(sh_hi + p * 8)         = make_uint4(hp[0], hp[1], hp[2], hp[3]);
        *(uint4*)(sh_hi + PLANE + p * 8) = make_uint4(hp[4], hp[5], hp[6], hp[7]);
        float wn = w[n0 + p];
        ws += wn;
        sh_p[p] = wn * __builtin_amdgcn_exp2f(-0.5f * LOG2E * dd);
    }
    #pragma unroll
    for (int off = 32; off > 0; off >>= 1) ws += __shfl_down(ws, off, 64);
    if (lane == 0) ls[wave] = ws;

    // ---- A fragment: bf16(L*x), row = col32, k = khalf*8 + j  (full K=16 used)
    bf16x8 afrag;
    {
        int q = qg * 32 + col32;
        const float* xp = X + (size_t)q * D + khalf * 8;
        #pragma unroll
        for (int j = 0; j < 8; j++)
            afrag[j] = (short)f2bf(xp[j] * LOG2E);
    }

    f32x16 dens, zc;
    #pragma unroll
    for (int r = 0; r < 16; r++) { dens[r] = 0.f; zc[r] = 0.f; }

    __syncthreads();

    if (threadIdx.x == 0)
        wpart[chunk] = (ls[0] + ls[1]) + (ls[2] + ls[3]);

    // ---- main loop: depth-1 LDS prefetch; MFMA(C=zero) -> exp2 -> fmac(p0)
    const int eoff = khalf * PLANE + col32 * 8;  // shorts
    bf16x8 b1 = *(const bf16x8*)(sh_hi + eoff);
    float  p0 = sh_p[col32];
    #pragma unroll 2
    for (int it = 0; it < cnt; it++) {
        bf16x8 nb1 = *(const bf16x8*)(sh_hi + (it + 1) * 256 + eoff);
        float  np0 = sh_p[(it + 1) * 32 + col32];
        f32x16 s = __builtin_amdgcn_mfma_f32_32x32x16_bf16(afrag, b1, zc, 0, 0, 0);
        #pragma unroll
        for (int r = 0; r < 16; r++)
            dens[r] = fmaf(p0, __builtin_amdgcn_exp2f(s[r]), dens[r]);
        b1 = nb1; p0 = np0;
    }

    // ---- reduce over the 32 n-lanes (cols), plain store (no atomics)
    #pragma unroll
    for (int r = 0; r < 16; r++) {
        float v = dens[r];
        v += __shfl_xor(v, 1, 64);
        v += __shfl_xor(v, 2, 64);
        v += __shfl_xor(v, 4, 64);
        v += __shfl_xor(v, 8, 64);
        v += __shfl_xor(v, 16, 64);
        if (col32 == 0) {
            int q = qg * 32 + (r & 3) + 8 * (r >> 2) + 4 * khalf;
            part[(size_t)chunk * Q + q] = v;
        }
    }
}

// ---------------- finalize: parallel chunk reduce + wave-parallel wsum + log ------
// 32 blocks x 256 threads; each block covers 64 queries, 4 threads per query
// (each summing 32 chunks, coalesced), LDS combine, 64 threads finalize.
__global__ __launch_bounds__(256) void fin_kernel(
        const float* __restrict__ X, const float* __restrict__ part,
        const float* __restrict__ wpart, float* __restrict__ out, int Q) {
    __shared__ float sred[4][FIN_QPB];
    __shared__ float swsum;

    const int tid = threadIdx.x;
    const int qi = tid & (FIN_QPB - 1);
    const int seg = tid >> 6;              // which 32-chunk segment (0..3)
    const int q = blockIdx.x * FIN_QPB + qi;

    // partial sum over this segment's 32 chunks (coalesced across qi lanes)
    float a0 = 0.f, a1 = 0.f, a2 = 0.f, a3 = 0.f;
    const int c0 = seg * 32;
    #pragma unroll 4
    for (int c = 0; c < 32; c += 4) {
        a0 += part[(size_t)(c0 + c + 0) * Q + q];
        a1 += part[(size_t)(c0 + c + 1) * Q + q];
        a2 += part[(size_t)(c0 + c + 2) * Q + q];
        a3 += part[(size_t)(c0 + c + 3) * Q + q];
    }
    sred[seg][qi] = (a0 + a1) + (a2 + a3);

    // wave 0: wsum via 2 loads/lane + shuffle reduce (128 chunks)
    if (tid < 64) {
        float wv = wpart[tid] + wpart[tid + 64];
        #pragma unroll
        for (int off = 32; off > 0; off >>= 1) wv += __shfl_down(wv, off, 64);
        if (tid == 0) swsum = wv;
    }
    __syncthreads();

    if (tid < FIN_QPB) {
        float dsum = (sred[0][tid] + sred[1][tid]) + (sred[2][tid] + sred[3][tid]);
        int qq = blockIdx.x * FIN_QPB + tid;
        const float4* xp = (const float4*)(X + (size_t)qq * D);
        float4 x0 = xp[0], x1 = xp[1], x2 = xp[2], x3 = xp[3];
        float xx = x0.x*x0.x + x0.y*x0.y + x0.z*x0.z + x0.w*x0.w
                 + x1.x*x1.x + x1.y*x1.y + x1.z*x1.z + x1.w*x1.w
                 + x2.x*x2.x + x2.y*x2.y + x2.z*x2.z + x2.w*x2.w
                 + x3.x*x3.x + x3.y*x3.y + x3.z*x3.z + x3.w*x3.w;
        float aq = -0.5f * LOG2E * xx;
        const float ln_norm = -8.f * 1.8378770664093453f;  // ln((2*pi)^-8)
        out[qq] = LN2 * (aq + __builtin_amdgcn_logf(dsum)
                            - __builtin_amdgcn_logf(swsum)) + ln_norm;
    }
}

extern "C" void kernel_launch(void* const* d_in, const int* in_sizes, int n_in,
                              void* d_out, int out_size, void* d_ws, size_t ws_size,
                              hipStream_t stream) {
    const float* X    = (const float*)d_in[0];
    const float* data = (const float*)d_in[1];
    const float* w    = (const float*)d_in[2];
    float* out = (float*)d_out;
    int Q = in_sizes[0] / D;   // 2048
    int N = in_sizes[1] / D;   // 100000

    // ws layout (floats): [0..NCH) wpart, then part (NCH*Q floats).
    // Everything written before read each launch -> no memset needed.
    float* wpart = (float*)d_ws;
    float* part  = wpart + NCH;

    dim3 grid(Q / (4 * 32), NCH);   // (16, 128)
    dens_kernel<<<grid, 256, 0, stream>>>(X, data, w, part, wpart, Q, N);

    fin_kernel<<<Q / FIN_QPB, 256, 0, stream>>>(X, part, wpart, out, Q);
}

// Round 11
// 91.964 us; speedup vs baseline: 1.2289x; 1.0002x over previous
//
#include <hip/hip_runtime.h>

#define D 16
#define NCH 128       // n-chunks: grid (16,128)=2048 blocks = 2 even rounds of
                      // 4 blocks/CU (launch_bounds(256,4) regime)
#define TILES_MAX 25  // ceil(3125/128) = 25 tiles of 32 points
#define FIN_QPB 64    // queries per fin block (x 4 segments of 32 chunks)

#define LOG2E 1.4426950408889634f
#define LN2   0.6931471805599453f

// k-half plane stride in shorts: (TILES_MAX+1) tiles * 32 pts * 8 shorts
#define PLANE ((TILES_MAX + 1) * 32 * 8)

typedef __attribute__((ext_vector_type(8)))  short bf16x8;
typedef __attribute__((ext_vector_type(16))) float f32x16;

__device__ __forceinline__ unsigned short f2bf(float f) {
    unsigned u = __float_as_uint(f);
    unsigned r = (u + 0x7fffu + ((u >> 16) & 1u)) >> 16;
    return (unsigned short)r;
}

// R17: re-anchor on R8 (last passing: 92.0us) and REMOVE the only
// state-dependent read in the program: the depth-1 prefetch's read of the
// uninitialized LDS pad tile. R9 (asm pins) and R10 (mfma pipeline) both
// diverged post-timing at exactly 0.75 across graph replays -> replay-varying
// state. The pad is now staged with deterministic zeros (sh_hi pad tile and
// sh_p pad row) before __syncthreads; prefetched pad values remain unused,
// but are now bit-identical on every call regardless of prior LDS contents.
// R10 datapoint kept in journal: mfma-lookahead == R8 timing -> dens is NOT
// MFMA-latency-bound; remaining cost is VALU/trans issue work.
// part[chunk][q] = sum_{n in chunk} p_n * exp2( L*(x_q.d_n) ),
// p_n = w_n * 2^(-0.5*L*|d_n|^2) precomputed in staging (R13 fold).
__global__ __launch_bounds__(256, 4) void dens_kernel(
        const float* __restrict__ X, const float* __restrict__ data,
        const float* __restrict__ w, float* __restrict__ part,
        float* __restrict__ wpart, int Q, int N) {
    // two k-half planes so the B-fragment is one ds_read_b128 per tile
    __shared__ unsigned short sh_hi[2 * PLANE];            // 26.6 KB
    __shared__ float          sh_p[(TILES_MAX + 1) * 32];  // 3.3 KB
    __shared__ float          ls[4];

    const int lane  = threadIdx.x & 63;
    const int wave  = threadIdx.x >> 6;
    const int col32 = lane & 31;       // B col / D col: n-index within tile
    const int khalf = lane >> 5;       // k-half (0: k0-7, 1: k8-15)

    const int qg = blockIdx.x * 4 + wave;   // q-tile of 32 queries per wave

    // ---- this block's n-tile range (tiles of 32 points)
    const int NT = N >> 5;                       // 3125
    const int base = NT / NCH, rem = NT % NCH;
    const int chunk = blockIdx.y;
    const int tile0 = chunk * base + min(chunk, rem);
    const int cnt = base + (chunk < rem ? 1 : 0);
    const int npts = cnt * 32;
    const int n0 = tile0 * 32;

    // ---- stage: fp32 -> bf16 pack into two k-half planes + per-point weight
    float ws = 0.f;
    for (int p = threadIdx.x; p < npts; p += 256) {
        const float4* dp = (const float4*)(data + (size_t)(n0 + p) * D);
        float4 v0 = dp[0], v1 = dp[1], v2 = dp[2], v3 = dp[3];
        float vv[16] = {v0.x, v0.y, v0.z, v0.w, v1.x, v1.y, v1.z, v1.w,
                        v2.x, v2.y, v2.z, v2.w, v3.x, v3.y, v3.z, v3.w};
        float dd = 0.f;
        unsigned hp[8];
        #pragma unroll
        for (int j = 0; j < 8; j++) {
            float a = vv[2 * j], b = vv[2 * j + 1];
            dd = fmaf(a, a, fmaf(b, b, dd));
            hp[j] = (unsigned)f2bf(a) | ((unsigned)f2bf(b) << 16);
        }
        *(uint4*)(sh_hi + p * 8)         = make_uint4(hp[0], hp[1], hp[2], hp[3]);
        *(uint4*)(sh_hi + PLANE + p * 8) = make_uint4(hp[4], hp[5], hp[6], hp[7]);
        float wn = w[n0 + p];
        ws += wn;
        sh_p[p] = wn * __builtin_amdgcn_exp2f(-0.5f * LOG2E * dd);
    }
    // deterministic pad tile (read by the depth-1 prefetch, never consumed):
    // 64 threads zero both k-half planes of tile `cnt`; 32 threads zero sh_p pad.
    if (threadIdx.x < 64) {
        int t = threadIdx.x;                 // 64 x 8 shorts = 512 shorts
        int half = t >> 5;                   // 0 -> plane0, 1 -> plane1
        int slot = t & 31;
        *(uint4*)(sh_hi + half * PLANE + (npts + slot) * 8) =
            make_uint4(0u, 0u, 0u, 0u);
        if (slot == t && t < 32) sh_p[npts + t] = 0.f;
    }
    #pragma unroll
    for (int off = 32; off > 0; off >>= 1) ws += __shfl_down(ws, off, 64);
    if (lane == 0) ls[wave] = ws;

    // ---- A fragment: bf16(L*x), row = col32, k = khalf*8 + j  (full K=16 used)
    bf16x8 afrag;
    {
        int q = qg * 32 + col32;
        const float* xp = X + (size_t)q * D + khalf * 8;
        #pragma unroll
        for (int j = 0; j < 8; j++)
            afrag[j] = (short)f2bf(xp[j] * LOG2E);
    }

    f32x16 dens, zc;
    #pragma unroll
    for (int r = 0; r < 16; r++) { dens[r] = 0.f; zc[r] = 0.f; }

    __syncthreads();

    if (threadIdx.x == 0)
        wpart[chunk] = (ls[0] + ls[1]) + (ls[2] + ls[3]);

    // ---- main loop: depth-1 LDS prefetch; MFMA(C=zero) -> exp2 -> fmac(p0)
    const int eoff = khalf * PLANE + col32 * 8;  // shorts
    bf16x8 b1 = *(const bf16x8*)(sh_hi + eoff);
    float  p0 = sh_p[col32];
    #pragma unroll 2
    for (int it = 0; it < cnt; it++) {
        bf16x8 nb1 = *(const bf16x8*)(sh_hi + (it + 1) * 256 + eoff);
        float  np0 = sh_p[(it + 1) * 32 + col32];
        f32x16 s = __builtin_amdgcn_mfma_f32_32x32x16_bf16(afrag, b1, zc, 0, 0, 0);
        #pragma unroll
        for (int r = 0; r < 16; r++)
            dens[r] = fmaf(p0, __builtin_amdgcn_exp2f(s[r]), dens[r]);
        b1 = nb1; p0 = np0;
    }

    // ---- reduce over the 32 n-lanes (cols), plain store (no atomics)
    #pragma unroll
    for (int r = 0; r < 16; r++) {
        float v = dens[r];
        v += __shfl_xor(v, 1, 64);
        v += __shfl_xor(v, 2, 64);
        v += __shfl_xor(v, 4, 64);
        v += __shfl_xor(v, 8, 64);
        v += __shfl_xor(v, 16, 64);
        if (col32 == 0) {
            int q = qg * 32 + (r & 3) + 8 * (r >> 2) + 4 * khalf;
            part[(size_t)chunk * Q + q] = v;
        }
    }
}

// ---------------- finalize: parallel chunk reduce + wave-parallel wsum + log ------
// 32 blocks x 256 threads; each block covers 64 queries, 4 threads per query
// (each summing 32 chunks, coalesced), LDS combine, 64 threads finalize.
__global__ __launch_bounds__(256) void fin_kernel(
        const float* __restrict__ X, const float* __restrict__ part,
        const float* __restrict__ wpart, float* __restrict__ out, int Q) {
    __shared__ float sred[4][FIN_QPB];
    __shared__ float swsum;

    const int tid = threadIdx.x;
    const int qi = tid & (FIN_QPB - 1);
    const int seg = tid >> 6;              // which 32-chunk segment (0..3)
    const int q = blockIdx.x * FIN_QPB + qi;

    // partial sum over this segment's 32 chunks (coalesced across qi lanes)
    float a0 = 0.f, a1 = 0.f, a2 = 0.f, a3 = 0.f;
    const int c0 = seg * 32;
    #pragma unroll 4
    for (int c = 0; c < 32; c += 4) {
        a0 += part[(size_t)(c0 + c + 0) * Q + q];
        a1 += part[(size_t)(c0 + c + 1) * Q + q];
        a2 += part[(size_t)(c0 + c + 2) * Q + q];
        a3 += part[(size_t)(c0 + c + 3) * Q + q];
    }
    sred[seg][qi] = (a0 + a1) + (a2 + a3);

    // wave 0: wsum via 2 loads/lane + shuffle reduce (128 chunks)
    if (tid < 64) {
        float wv = wpart[tid] + wpart[tid + 64];
        #pragma unroll
        for (int off = 32; off > 0; off >>= 1) wv += __shfl_down(wv, off, 64);
        if (tid == 0) swsum = wv;
    }
    __syncthreads();

    if (tid < FIN_QPB) {
        float dsum = (sred[0][tid] + sred[1][tid]) + (sred[2][tid] + sred[3][tid]);
        int qq = blockIdx.x * FIN_QPB + tid;
        const float4* xp = (const float4*)(X + (size_t)qq * D);
        float4 x0 = xp[0], x1 = xp[1], x2 = xp[2], x3 = xp[3];
        float xx = x0.x*x0.x + x0.y*x0.y + x0.z*x0.z + x0.w*x0.w
                 + x1.x*x1.x + x1.y*x1.y + x1.z*x1.z + x1.w*x1.w
                 + x2.x*x2.x + x2.y*x2.y + x2.z*x2.z + x2.w*x2.w
                 + x3.x*x3.x + x3.y*x3.y + x3.z*x3.z + x3.w*x3.w;
        float aq = -0.5f * LOG2E * xx;
        const float ln_norm = -8.f * 1.8378770664093453f;  // ln((2*pi)^-8)
        out[qq] = LN2 * (aq + __builtin_amdgcn_logf(dsum)
                            - __builtin_amdgcn_logf(swsum)) + ln_norm;
    }
}

extern "C" void kernel_launch(void* const* d_in, const int* in_sizes, int n_in,
                              void* d_out, int out_size, void* d_ws, size_t ws_size,
                              hipStream_t stream) {
    const float* X    = (const float*)d_in[0];
    const float* data = (const float*)d_in[1];
    const float* w    = (const float*)d_in[2];
    float* out = (float*)d_out;
    int Q = in_sizes[0] / D;   // 2048
    int N = in_sizes[1] / D;   // 100000

    // ws layout (floats): [0..NCH) wpart, then part (NCH*Q floats).
    // Everything written before read each launch -> no memset needed.
    float* wpart = (float*)d_ws;
    float* part  = wpart + NCH;

    dim3 grid(Q / (4 * 32), NCH);   // (16, 128)
    dens_kernel<<<grid, 256, 0, stream>>>(X, data, w, part, wpart, Q, N);

    fin_kernel<<<Q / FIN_QPB, 256, 0, stream>>>(X, part, wpart, out, Q);
}